// Round 17
// baseline (31.501 us; speedup 1.0000x reference)
//
#include <hip/hip_runtime.h>
#include <math.h>

constexpr int Bb = 4, Cc = 64, Hh = 256, Ww = 256;
constexpr int RR = 2;             // output rows per block
constexpr int NSTRIP = Hh / RR;   // 128
constexpr int NBLK = Bb * NSTRIP; // 512 entropy blocks
constexpr int NPX = Bb * Hh * Ww; // 262144 output pixels
constexpr int NPX4 = NPX / 4;

#define LOG2E 1.44269504088896340736f
#define LN2   0.69314718055994530942f

__device__ __forceinline__ unsigned int fenc(float f) {
  unsigned int u = __float_as_uint(f);
  return (u & 0x80000000u) ? ~u : (u | 0x80000000u);
}
__device__ __forceinline__ float fdec(unsigned int k) {
  return __uint_as_float((k & 0x80000000u) ? (k ^ 0x80000000u) : ~k);
}

// entropy = ln(s) - ws/s, s = 3x3 box of e^v, ws = 3x3 box of v*e^v
// (shift-invariant softmax entropy; N(0,1) inputs so e^v safe in fp32).
// Normalization is affine-invariant -> raw channel sums are normalized.
//
// CS=1 full-width geometry (kills the combine dispatch): block (64,16) =
// 16 waves; lane = 4 cols (float4, full 256-col row -> halos are image
// edges = compile-time constants, NO extra edge loads — r14's mistakes
// fixed); ty = 4 channels each (rolled cc loop). Each block: RR=2 output
// rows x FULL 64-channel sum -> block-local min/max, no combine needed.
// Grid: b(4) x strip(128) = 512 blocks x 16 waves = 8192 waves.
// Per-thread state ~55 regs (r5-proven ring body, smaller acc) -> fits the
// 64-VGPR / 2-blocks-per-CU line at 1024-thread blocks.
// FB=0: e + per-block min/max -> pm[bx] non-atomic (no init needed).
// FB=1: fallback, e direct + atomicMin/Max into stats (pre-memset).
// NOTE: plain __launch_bounds__(1024) — min-waves hints spill (r6/r7).
template <int FB>
__global__ __launch_bounds__(1024) void entropy_kernel(const float* __restrict__ x,
                                                       float* __restrict__ e,
                                                       float* __restrict__ pm,
                                                       unsigned int* __restrict__ stats) {
  const int bx = blockIdx.x;
  const int strip = bx & (NSTRIP - 1);
  const int b = bx >> 7;
  const int r0 = strip * RR;
  const int tx = threadIdx.x;   // 0..63
  const int ty = threadIdx.y;   // 0..15
  const int w0 = tx * 4;

  const size_t planeStride = (size_t)Hh * Ww;
  const float* xb = x + ((size_t)b * Cc + ty * 4) * planeStride + w0;

  float acc[RR][4];
#pragma unroll
  for (int o = 0; o < RR; ++o)
#pragma unroll
    for (int i = 0; i < 4; ++i) acc[o][i] = 0.f;

#pragma unroll 1
  for (int cc = 0; cc < 4; ++cc) {
    const float* plane = xb + (size_t)cc * planeStride;

    float ha[3][4], hb[3][4];
#pragma unroll
    for (int j = 0; j < RR + 2; ++j) {      // 4 rows
      const int row = r0 - 1 + j;
      float4 v = make_float4(0.f, 0.f, 0.f, 0.f);
      if (row >= 0 && row < Hh)
        v = *reinterpret_cast<const float4*>(plane + (size_t)row * Ww);
      const float* vp = &v.x;
      float a[4], bb4[4];
#pragma unroll
      for (int i = 0; i < 4; ++i) {
        float t = __builtin_amdgcn_exp2f(vp[i] * LOG2E);  // e^v
        a[i] = t;
        bb4[i] = vp[i] * t;                               // v * e^v
      }
      float la = __shfl_up(a[3], 1, 64);
      float lb = __shfl_up(bb4[3], 1, 64);
      float ra = __shfl_down(a[0], 1, 64);
      float rb = __shfl_down(bb4[0], 1, 64);
      la = (tx == 0) ? 1.f : la;   lb = (tx == 0) ? 0.f : lb;
      ra = (tx == 63) ? 1.f : ra;  rb = (tx == 63) ? 0.f : rb;
      const int s0 = j % 3;  // compile-time (loop unrolled)
      ha[s0][0] = la + a[0] + a[1];
      ha[s0][1] = a[0] + a[1] + a[2];
      ha[s0][2] = a[1] + a[2] + a[3];
      ha[s0][3] = a[2] + a[3] + ra;
      hb[s0][0] = lb + bb4[0] + bb4[1];
      hb[s0][1] = bb4[0] + bb4[1] + bb4[2];
      hb[s0][2] = bb4[1] + bb4[2] + bb4[3];
      hb[s0][3] = bb4[2] + bb4[3] + rb;
      if (j >= 2) {
        const int orow = j - 2;   // compile-time
#pragma unroll
        for (int i = 0; i < 4; ++i) {
          float s = ha[0][i] + ha[1][i] + ha[2][i];
          float w = hb[0][i] + hb[1][i] + hb[2][i];
          acc[orow][i] += LN2 * __builtin_amdgcn_logf(s) -
                          w * __builtin_amdgcn_rcpf(s);
        }
      }
    }
  }

  // Reduce the 16 ty channel groups (32 KiB LDS) -> full 64-channel sums.
  __shared__ float red[16][RR][4][64];
#pragma unroll
  for (int o = 0; o < RR; ++o)
#pragma unroll
    for (int i = 0; i < 4; ++i) red[ty][o][i][tx] = acc[o][i];
  __syncthreads();

  float mn = INFINITY, mx = -INFINITY;
  if (ty < RR) {
    const size_t px = (size_t)(b * Hh + r0 + ty) * Ww + w0;
    float vsum[4];
#pragma unroll
    for (int i = 0; i < 4; ++i) {
      float t = 0.f;
#pragma unroll
      for (int g = 0; g < 16; ++g) t += red[g][ty][i][tx];
      vsum[i] = t;
    }
    *reinterpret_cast<float4*>(e + px) =
        make_float4(vsum[0], vsum[1], vsum[2], vsum[3]);
    mn = fminf(fminf(vsum[0], vsum[1]), fminf(vsum[2], vsum[3]));
    mx = fmaxf(fmaxf(vsum[0], vsum[1]), fmaxf(vsum[2], vsum[3]));
#pragma unroll
    for (int off = 32; off > 0; off >>= 1) {
      mn = fminf(mn, __shfl_down(mn, off, 64));
      mx = fmaxf(mx, __shfl_down(mx, off, 64));
    }
  }
  __shared__ float smn[RR], smx[RR];
  if (ty < RR && tx == 0) { smn[ty] = mn; smx[ty] = mx; }
  __syncthreads();
  if (ty == 0 && tx == 0) {
    mn = fminf(smn[0], smn[1]);
    mx = fmaxf(smx[0], smx[1]);
    if (FB == 0) {
      pm[bx] = mn;          // every slot written -> no init
      pm[NBLK + bx] = mx;
    } else {
      atomicMin(&stats[b], fenc(mn));
      atomicMax(&stats[4 + b], fenc(mx));
    }
  }
}

// Reduce this batch's 128 pm pairs in-block (no atomics), then normalize.
// Grid 256 blocks x 256 threads, one float4 per thread. Batch b = bx>>6;
// its entropy blocks are pm[b*128 .. b*128+127].
__global__ __launch_bounds__(256) void norm_ws(float* __restrict__ e,
                                               const float* __restrict__ pm) {
  const int bx = blockIdx.x;
  const int b = bx >> 6;
  const int k = threadIdx.x & 127;   // waves 2,3 duplicate waves 0,1 (harmless)
  float mn = pm[b * 128 + k];
  float mx = pm[NBLK + b * 128 + k];
#pragma unroll
  for (int off = 32; off > 0; off >>= 1) {
    mn = fminf(mn, __shfl_down(mn, off, 64));
    mx = fmaxf(mx, __shfl_down(mx, off, 64));
  }
  __shared__ float smn[4], smx[4];
  const int wave = threadIdx.x >> 6;
  if ((threadIdx.x & 63) == 0) { smn[wave] = mn; smx[wave] = mx; }
  __syncthreads();
  mn = fminf(fminf(smn[0], smn[1]), fminf(smn[2], smn[3]));
  mx = fmaxf(fmaxf(smx[0], smx[1]), fmaxf(smx[2], smx[3]));
  const float inv = 1.0f / fmaxf(mx - mn, 1e-6f);

  const int t = bx * 256 + threadIdx.x;
  float4 v = reinterpret_cast<float4*>(e)[t];
  v.x = (v.x - mn) * inv;
  v.y = (v.y - mn) * inv;
  v.z = (v.z - mn) * inv;
  v.w = (v.w - mn) * inv;
  reinterpret_cast<float4*>(e)[t] = v;
}

// Fallback normalize from atomic stats.
__global__ __launch_bounds__(256) void norm_atomic(float* __restrict__ e,
                                                   const unsigned int* __restrict__ stats) {
  const int t = blockIdx.x * 256 + threadIdx.x;
  const int b = t >> 14;
  const float mn = fdec(stats[b]);
  const float mx = fdec(stats[4 + b]);
  const float inv = 1.0f / fmaxf(mx - mn, 1e-6f);
  float4 v = reinterpret_cast<float4*>(e)[t];
  v.x = (v.x - mn) * inv;
  v.y = (v.y - mn) * inv;
  v.z = (v.z - mn) * inv;
  v.w = (v.w - mn) * inv;
  reinterpret_cast<float4*>(e)[t] = v;
}

extern "C" void kernel_launch(void* const* d_in, const int* in_sizes, int n_in,
                              void* d_out, int out_size, void* d_ws, size_t ws_size,
                              hipStream_t stream) {
  const float* x = (const float*)d_in[0];
  float* out = (float*)d_out;

  const size_t ws_needed = (size_t)(2 * NBLK) * sizeof(float);  // 4 KB
  if (ws_size >= ws_needed) {
    float* pm = (float*)d_ws;  // [NBLK min][NBLK max]
    entropy_kernel<0><<<dim3(NBLK), dim3(64, 16), 0, stream>>>(x, out, pm, nullptr);
    norm_ws<<<dim3(NPX4 / 256), dim3(256), 0, stream>>>(out, pm);
  } else {
    unsigned int* stats = (unsigned int*)d_ws;  // 8 uints
    hipMemsetAsync(stats, 0xFF, 4 * sizeof(unsigned int), stream);
    hipMemsetAsync(stats + 4, 0x00, 4 * sizeof(unsigned int), stream);
    entropy_kernel<1><<<dim3(NBLK), dim3(64, 16), 0, stream>>>(x, out, nullptr, stats);
    norm_atomic<<<dim3(NPX4 / 256), dim3(256), 0, stream>>>(out, stats);
  }
}

// Round 18
// 29.223 us; speedup vs baseline: 1.0780x; 1.0780x over previous
//
#include <hip/hip_runtime.h>
#include <math.h>

constexpr int Bb = 4, Cc = 64, Hh = 256, Ww = 256;
constexpr int RR = 4;             // output rows per block (amp 1.5x)
constexpr int NSTRIP = Hh / RR;   // 64
constexpr int NPX = Bb * Hh * Ww; // 262144 output pixels
constexpr int NPX4 = NPX / 4;

#define LOG2E 1.44269504088896340736f
#define LN2   0.69314718055994530942f

__device__ __forceinline__ unsigned int fenc(float f) {
  unsigned int u = __float_as_uint(f);
  return (u & 0x80000000u) ? ~u : (u | 0x80000000u);
}
__device__ __forceinline__ float fdec(unsigned int k) {
  return __uint_as_float((k & 0x80000000u) ? (k ^ 0x80000000u) : ~k);
}

// entropy = ln(s) - ws/s, s = 3x3 box of e^v, ws = 3x3 box of v*e^v
// (shift-invariant softmax entropy). Normalization is affine-invariant ->
// raw channel sums are normalized.
//
// CSK = channel-split factor. Block (64,8), ty covers 64/(CSK*8) channels.
// CSK=8: 1 channel/ty, rows STREAMED (no 6-float4 preload) -> per-thread
// state ~60 regs, targeting the <=64-VGPR / 8-waves-per-SIMD occupancy
// class (r8 showed the 2ch/ty body sits at 108 VGPR = 4 waves/SIMD and is
// latency-bound). Grid: b(4) x strip(64) x cs(CSK).
//   DST=0: non-atomic store of channel partial into pw[cs][...]
//   DST=1: atomicAdd into e (fallback; e pre-zeroed)
// NOTE: plain __launch_bounds__(512) only — min-waves hints spill (r6/r7).
// All acc indices compile-time (r15 lesson: runtime idx -> scratch).
template <int CSK, int DST>
__global__ __launch_bounds__(512) void entropy_kernel(const float* __restrict__ x,
                                                      float* __restrict__ out) {
  constexpr int NCC = Cc / (CSK * 8);   // channels per ty
  const int bx = blockIdx.x;
  const int cs = bx % CSK;
  const int rest = bx / CSK;
  const int strip = rest % NSTRIP;
  const int b = rest / NSTRIP;
  const int r0 = strip * RR;
  const int tx = threadIdx.x;   // 0..63
  const int ty = threadIdx.y;   // 0..7
  const int w0 = tx * 4;

  const size_t planeStride = (size_t)Hh * Ww;
  const float* xb = x + ((size_t)b * Cc + cs * (NCC * 8) + ty * NCC) * planeStride + w0;

  float acc[RR][4];
#pragma unroll
  for (int o = 0; o < RR; ++o)
#pragma unroll
    for (int i = 0; i < 4; ++i) acc[o][i] = 0.f;

#pragma unroll 1
  for (int cc = 0; cc < NCC; ++cc) {
    const float* plane = xb + (size_t)cc * planeStride;

    float ha[3][4], hb[3][4];
#pragma unroll
    for (int j = 0; j < RR + 2; ++j) {   // stream one row at a time
      const int row = r0 - 1 + j;
      float4 v = make_float4(0.f, 0.f, 0.f, 0.f);
      if (row >= 0 && row < Hh)
        v = *reinterpret_cast<const float4*>(plane + (size_t)row * Ww);
      const float* vp = &v.x;
      float a[4], bb4[4];
#pragma unroll
      for (int i = 0; i < 4; ++i) {
        float t = __builtin_amdgcn_exp2f(vp[i] * LOG2E);  // e^v
        a[i] = t;
        bb4[i] = vp[i] * t;                               // v * e^v
      }
      float la = __shfl_up(a[3], 1, 64);
      float lb = __shfl_up(bb4[3], 1, 64);
      float ra = __shfl_down(a[0], 1, 64);
      float rb = __shfl_down(bb4[0], 1, 64);
      la = (tx == 0) ? 1.f : la;   lb = (tx == 0) ? 0.f : lb;
      ra = (tx == 63) ? 1.f : ra;  rb = (tx == 63) ? 0.f : rb;
      // Sliding-window horizontal sums (6 adds instead of 8).
      const int s0 = j % 3;  // compile-time (loop unrolled)
      {
        float t01 = a[0] + a[1], t23 = a[2] + a[3];
        ha[s0][0] = la + t01;
        ha[s0][1] = t01 + a[2];
        ha[s0][2] = a[1] + t23;
        ha[s0][3] = t23 + ra;
      }
      {
        float t01 = bb4[0] + bb4[1], t23 = bb4[2] + bb4[3];
        hb[s0][0] = lb + t01;
        hb[s0][1] = t01 + bb4[2];
        hb[s0][2] = bb4[1] + t23;
        hb[s0][3] = t23 + rb;
      }
      if (j >= 2) {
        const int orow = j - 2;   // compile-time
#pragma unroll
        for (int i = 0; i < 4; ++i) {
          float s = ha[0][i] + ha[1][i] + ha[2][i];
          float w = hb[0][i] + hb[1][i] + hb[2][i];
          acc[orow][i] += LN2 * __builtin_amdgcn_logf(s) -
                          w * __builtin_amdgcn_rcpf(s);
        }
      }
    }
  }

  // Reduce the 8 ty groups (32 KiB LDS).
  __shared__ float red[8][RR][4][64];
#pragma unroll
  for (int o = 0; o < RR; ++o)
#pragma unroll
    for (int i = 0; i < 4; ++i) red[ty][o][i][tx] = acc[o][i];
  __syncthreads();
  if (ty < RR) {
    const size_t px = (size_t)(b * Hh + r0 + ty) * Ww + w0;
    float vsum[4];
#pragma unroll
    for (int i = 0; i < 4; ++i) {
      float t = 0.f;
#pragma unroll
      for (int g = 0; g < 8; ++g) t += red[g][ty][i][tx];
      vsum[i] = t;
    }
    if (DST == 0) {
      *reinterpret_cast<float4*>(out + (size_t)cs * NPX + px) =
          make_float4(vsum[0], vsum[1], vsum[2], vsum[3]);
    } else {
#pragma unroll
      for (int i = 0; i < 4; ++i) atomicAdd(out + px + i, vsum[i]);
    }
  }
}

// ws path K2: combine the CSK channel partials, write e, emit per-block
// min/max partials (every slot written -> no init). Grid 256 x 256 threads.
template <int CSK>
__global__ __launch_bounds__(256) void combine_minmax(const float* __restrict__ pw,
                                                      float* __restrict__ e,
                                                      float* __restrict__ pm) {
  const int t = blockIdx.x * 256 + threadIdx.x;
  float4 v = reinterpret_cast<const float4*>(pw)[t];
#pragma unroll
  for (int k = 1; k < CSK; ++k) {
    float4 u = reinterpret_cast<const float4*>(pw + (size_t)k * NPX)[t];
    v.x += u.x; v.y += u.y; v.z += u.z; v.w += u.w;
  }
  reinterpret_cast<float4*>(e)[t] = v;

  float mn = fminf(fminf(v.x, v.y), fminf(v.z, v.w));
  float mx = fmaxf(fmaxf(v.x, v.y), fmaxf(v.z, v.w));
#pragma unroll
  for (int off = 32; off > 0; off >>= 1) {
    mn = fminf(mn, __shfl_down(mn, off, 64));
    mx = fmaxf(mx, __shfl_down(mx, off, 64));
  }
  __shared__ float smn[4], smx[4];
  const int wave = threadIdx.x >> 6;
  if ((threadIdx.x & 63) == 0) { smn[wave] = mn; smx[wave] = mx; }
  __syncthreads();
  if (threadIdx.x == 0) {
    pm[blockIdx.x]       = fminf(fminf(smn[0], smn[1]), fminf(smn[2], smn[3]));
    pm[256 + blockIdx.x] = fmaxf(fmaxf(smx[0], smx[1]), fmaxf(smx[2], smx[3]));
  }
}

// ws path K3: reduce this batch's 64 min/max partials in-wave, normalize.
__global__ __launch_bounds__(256) void norm_ws(float* __restrict__ e,
                                               const float* __restrict__ pm) {
  const int b = blockIdx.x >> 6;
  const int lane = threadIdx.x & 63;
  float mn = pm[b * 64 + lane];
  float mx = pm[256 + b * 64 + lane];
#pragma unroll
  for (int off = 32; off > 0; off >>= 1) {
    mn = fminf(mn, __shfl_down(mn, off, 64));
    mx = fmaxf(mx, __shfl_down(mx, off, 64));
  }
  mn = __shfl(mn, 0, 64);
  mx = __shfl(mx, 0, 64);
  const float inv = 1.0f / fmaxf(mx - mn, 1e-6f);

  const int t = blockIdx.x * 256 + threadIdx.x;
  float4 v = reinterpret_cast<float4*>(e)[t];
  v.x = (v.x - mn) * inv;
  v.y = (v.y - mn) * inv;
  v.z = (v.z - mn) * inv;
  v.w = (v.w - mn) * inv;
  reinterpret_cast<float4*>(e)[t] = v;
}

// Fallback path kernels (atomics + memset) — used only if ws is tiny.
__global__ __launch_bounds__(256) void minmax_atomic(const float* __restrict__ e,
                                                     unsigned int* __restrict__ stats) {
  const int bx = blockIdx.x;
  const int b = bx >> 6;
  const float4 v = reinterpret_cast<const float4*>(
      e + (size_t)b * Hh * Ww + (bx & 63) * 1024)[threadIdx.x];
  float mn = fminf(fminf(v.x, v.y), fminf(v.z, v.w));
  float mx = fmaxf(fmaxf(v.x, v.y), fmaxf(v.z, v.w));
#pragma unroll
  for (int off = 32; off > 0; off >>= 1) {
    mn = fminf(mn, __shfl_down(mn, off, 64));
    mx = fmaxf(mx, __shfl_down(mx, off, 64));
  }
  __shared__ float smn[4], smx[4];
  const int wave = threadIdx.x >> 6;
  if ((threadIdx.x & 63) == 0) { smn[wave] = mn; smx[wave] = mx; }
  __syncthreads();
  if (threadIdx.x == 0) {
    atomicMin(&stats[b], fenc(fminf(fminf(smn[0], smn[1]), fminf(smn[2], smn[3]))));
    atomicMax(&stats[4 + b], fenc(fmaxf(fmaxf(smx[0], smx[1]), fmaxf(smx[2], smx[3]))));
  }
}

__global__ __launch_bounds__(256) void norm_atomic(float* __restrict__ e,
                                                   const unsigned int* __restrict__ stats) {
  const int t = blockIdx.x * 256 + threadIdx.x;
  const int b = t >> 14;
  const float mn = fdec(stats[b]);
  const float mx = fdec(stats[4 + b]);
  const float inv = 1.0f / fmaxf(mx - mn, 1e-6f);
  float4 v = reinterpret_cast<float4*>(e)[t];
  v.x = (v.x - mn) * inv;
  v.y = (v.y - mn) * inv;
  v.z = (v.z - mn) * inv;
  v.w = (v.w - mn) * inv;
  reinterpret_cast<float4*>(e)[t] = v;
}

extern "C" void kernel_launch(void* const* d_in, const int* in_sizes, int n_in,
                              void* d_out, int out_size, void* d_ws, size_t ws_size,
                              hipStream_t stream) {
  const float* x = (const float*)d_in[0];
  float* out = (float*)d_out;

  const size_t need8 = ((size_t)8 * NPX + 512) * sizeof(float);  // ~8.4 MB
  const size_t need4 = ((size_t)4 * NPX + 512) * sizeof(float);  // ~4.2 MB
  if (ws_size >= need8) {
    float* pw = (float*)d_ws;                 // [8][NPX] partials
    float* pm = pw + (size_t)8 * NPX;         // [256 min][256 max]
    entropy_kernel<8, 0><<<dim3(Bb * NSTRIP * 8), dim3(64, 8), 0, stream>>>(x, pw);
    combine_minmax<8><<<dim3(NPX4 / 256), dim3(256), 0, stream>>>(pw, out, pm);
    norm_ws<<<dim3(NPX4 / 256), dim3(256), 0, stream>>>(out, pm);
  } else if (ws_size >= need4) {
    float* pw = (float*)d_ws;                 // [4][NPX] partials
    float* pm = pw + (size_t)4 * NPX;
    entropy_kernel<4, 0><<<dim3(Bb * NSTRIP * 4), dim3(64, 8), 0, stream>>>(x, pw);
    combine_minmax<4><<<dim3(NPX4 / 256), dim3(256), 0, stream>>>(pw, out, pm);
    norm_ws<<<dim3(NPX4 / 256), dim3(256), 0, stream>>>(out, pm);
  } else {
    unsigned int* stats = (unsigned int*)d_ws;  // 8 uints
    hipMemsetAsync(out, 0, (size_t)NPX * sizeof(float), stream);
    hipMemsetAsync(stats, 0xFF, 4 * sizeof(unsigned int), stream);
    hipMemsetAsync(stats + 4, 0x00, 4 * sizeof(unsigned int), stream);
    entropy_kernel<4, 1><<<dim3(Bb * NSTRIP * 4), dim3(64, 8), 0, stream>>>(x, out);
    minmax_atomic<<<dim3(Bb * 64), dim3(256), 0, stream>>>(out, stats);
    norm_atomic<<<dim3(NPX4 / 256), dim3(256), 0, stream>>>(out, stats);
  }
}

// Round 19
// 24.493 us; speedup vs baseline: 1.2861x; 1.1931x over previous
//
#include <hip/hip_runtime.h>
#include <math.h>

constexpr int Bb = 4, Cc = 64, Hh = 256, Ww = 256;
constexpr int RR = 4;             // output rows per block (amp 1.5x)
constexpr int NSTRIP = Hh / RR;   // 64
constexpr int NBLK = Bb * NSTRIP; // 256 entropy blocks = 1 per CU
constexpr int NPX = Bb * Hh * Ww; // 262144 output pixels
constexpr int NPX4 = NPX / 4;

#define LOG2E 1.44269504088896340736f
#define LN2   0.69314718055994530942f

__device__ __forceinline__ unsigned int fenc(float f) {
  unsigned int u = __float_as_uint(f);
  return (u & 0x80000000u) ? ~u : (u | 0x80000000u);
}
__device__ __forceinline__ float fdec(unsigned int k) {
  return __uint_as_float((k & 0x80000000u) ? (k ^ 0x80000000u) : ~k);
}

// entropy = ln(s) - ws/s, s = 3x3 box of e^v, ws = 3x3 box of v*e^v
// (shift-invariant softmax entropy). Normalization is affine-invariant ->
// raw channel sums are normalized.
//
// CS=1 full-channel geometry, combine dispatch eliminated:
// block (64,16) = 16 waves; lane = 4 cols (float4, full 256-col row, halos
// are image edges = constants); ty = 4 channels each (rolled cc loop,
// streaming ring body — r5's proven ~52-VGPR shape). RR=4 rows per block.
// Grid = b(4) x strip(64) = 256 blocks = EXACTLY 1 block/CU: residency is
// guaranteed for any VGPR<=128 (no 2-blocks/CU requirement — r17's CS=1
// failed partly because grid 512 of 1024-thr blocks needed VGPR<=64).
// Block holds the FULL 64-channel sum for its 4 rows -> block min/max ->
// pm[bx] non-atomic (every slot written, no init).
// FB=1 fallback: atomicMin/Max into stats (pre-memset).
// NOTE: plain __launch_bounds__(1024) — min-waves hints spill (r6/r7).
// All acc indices compile-time (r15: runtime idx -> scratch).
template <int FB>
__global__ __launch_bounds__(1024) void entropy_kernel(const float* __restrict__ x,
                                                       float* __restrict__ e,
                                                       float* __restrict__ pm,
                                                       unsigned int* __restrict__ stats) {
  const int bx = blockIdx.x;
  const int strip = bx & (NSTRIP - 1);
  const int b = bx >> 6;
  const int r0 = strip * RR;
  const int tx = threadIdx.x;   // 0..63
  const int ty = threadIdx.y;   // 0..15
  const int w0 = tx * 4;

  const size_t planeStride = (size_t)Hh * Ww;
  const float* xb = x + ((size_t)b * Cc + ty * 4) * planeStride + w0;

  float acc[RR][4];
#pragma unroll
  for (int o = 0; o < RR; ++o)
#pragma unroll
    for (int i = 0; i < 4; ++i) acc[o][i] = 0.f;

#pragma unroll 1
  for (int cc = 0; cc < 4; ++cc) {
    const float* plane = xb + (size_t)cc * planeStride;

    float ha[3][4], hb[3][4];
#pragma unroll
    for (int j = 0; j < RR + 2; ++j) {   // stream one row at a time
      const int row = r0 - 1 + j;
      float4 v = make_float4(0.f, 0.f, 0.f, 0.f);
      if (row >= 0 && row < Hh)
        v = *reinterpret_cast<const float4*>(plane + (size_t)row * Ww);
      const float* vp = &v.x;
      float a[4], bb4[4];
#pragma unroll
      for (int i = 0; i < 4; ++i) {
        float t = __builtin_amdgcn_exp2f(vp[i] * LOG2E);  // e^v
        a[i] = t;
        bb4[i] = vp[i] * t;                               // v * e^v
      }
      float la = __shfl_up(a[3], 1, 64);
      float lb = __shfl_up(bb4[3], 1, 64);
      float ra = __shfl_down(a[0], 1, 64);
      float rb = __shfl_down(bb4[0], 1, 64);
      la = (tx == 0) ? 1.f : la;   lb = (tx == 0) ? 0.f : lb;
      ra = (tx == 63) ? 1.f : ra;  rb = (tx == 63) ? 0.f : rb;
      // Sliding-window horizontal sums.
      const int s0 = j % 3;  // compile-time (loop unrolled)
      {
        float t01 = a[0] + a[1], t23 = a[2] + a[3];
        ha[s0][0] = la + t01;
        ha[s0][1] = t01 + a[2];
        ha[s0][2] = a[1] + t23;
        ha[s0][3] = t23 + ra;
      }
      {
        float t01 = bb4[0] + bb4[1], t23 = bb4[2] + bb4[3];
        hb[s0][0] = lb + t01;
        hb[s0][1] = t01 + bb4[2];
        hb[s0][2] = bb4[1] + t23;
        hb[s0][3] = t23 + rb;
      }
      if (j >= 2) {
        const int orow = j - 2;   // compile-time
#pragma unroll
        for (int i = 0; i < 4; ++i) {
          float s = ha[0][i] + ha[1][i] + ha[2][i];
          float w = hb[0][i] + hb[1][i] + hb[2][i];
          acc[orow][i] += LN2 * __builtin_amdgcn_logf(s) -
                          w * __builtin_amdgcn_rcpf(s);
        }
      }
    }
  }

  // Reduce the 16 ty channel groups (64 KiB LDS, fine at 1 block/CU).
  __shared__ float red[16][RR][4][64];
#pragma unroll
  for (int o = 0; o < RR; ++o)
#pragma unroll
    for (int i = 0; i < 4; ++i) red[ty][o][i][tx] = acc[o][i];
  __syncthreads();

  float mn = INFINITY, mx = -INFINITY;
  if (ty < RR) {
    const size_t px = (size_t)(b * Hh + r0 + ty) * Ww + w0;
    float vsum[4];
#pragma unroll
    for (int i = 0; i < 4; ++i) {
      float t = 0.f;
#pragma unroll
      for (int g = 0; g < 16; ++g) t += red[g][ty][i][tx];
      vsum[i] = t;
    }
    *reinterpret_cast<float4*>(e + px) =
        make_float4(vsum[0], vsum[1], vsum[2], vsum[3]);
    mn = fminf(fminf(vsum[0], vsum[1]), fminf(vsum[2], vsum[3]));
    mx = fmaxf(fmaxf(vsum[0], vsum[1]), fmaxf(vsum[2], vsum[3]));
#pragma unroll
    for (int off = 32; off > 0; off >>= 1) {
      mn = fminf(mn, __shfl_down(mn, off, 64));
      mx = fmaxf(mx, __shfl_down(mx, off, 64));
    }
  }
  __shared__ float smn[RR], smx[RR];
  if (ty < RR && tx == 0) { smn[ty] = mn; smx[ty] = mx; }
  __syncthreads();
  if (ty == 0 && tx == 0) {
    mn = fminf(fminf(smn[0], smn[1]), fminf(smn[2], smn[3]));
    mx = fmaxf(fmaxf(smx[0], smx[1]), fmaxf(smx[2], smx[3]));
    if (FB == 0) {
      pm[bx] = mn;           // every slot written -> no init
      pm[NBLK + bx] = mx;
    } else {
      atomicMin(&stats[b], fenc(mn));
      atomicMax(&stats[4 + b], fenc(mx));
    }
  }
}

// Reduce this batch's 64 pm pairs in one wave, then normalize.
// Grid 256 blocks x 256 threads, one float4 per thread. Batch b = bx>>6;
// its entropy blocks are pm[b*64 .. b*64+63].
__global__ __launch_bounds__(256) void norm_ws(float* __restrict__ e,
                                               const float* __restrict__ pm) {
  const int bx = blockIdx.x;
  const int b = bx >> 6;
  const int lane = threadIdx.x & 63;
  float mn = pm[b * 64 + lane];
  float mx = pm[NBLK + b * 64 + lane];
#pragma unroll
  for (int off = 32; off > 0; off >>= 1) {
    mn = fminf(mn, __shfl_down(mn, off, 64));
    mx = fmaxf(mx, __shfl_down(mx, off, 64));
  }
  mn = __shfl(mn, 0, 64);
  mx = __shfl(mx, 0, 64);
  const float inv = 1.0f / fmaxf(mx - mn, 1e-6f);

  const int t = bx * 256 + threadIdx.x;
  float4 v = reinterpret_cast<float4*>(e)[t];
  v.x = (v.x - mn) * inv;
  v.y = (v.y - mn) * inv;
  v.z = (v.z - mn) * inv;
  v.w = (v.w - mn) * inv;
  reinterpret_cast<float4*>(e)[t] = v;
}

// Fallback normalize from atomic stats.
__global__ __launch_bounds__(256) void norm_atomic(float* __restrict__ e,
                                                   const unsigned int* __restrict__ stats) {
  const int t = blockIdx.x * 256 + threadIdx.x;
  const int b = t >> 14;
  const float mn = fdec(stats[b]);
  const float mx = fdec(stats[4 + b]);
  const float inv = 1.0f / fmaxf(mx - mn, 1e-6f);
  float4 v = reinterpret_cast<float4*>(e)[t];
  v.x = (v.x - mn) * inv;
  v.y = (v.y - mn) * inv;
  v.z = (v.z - mn) * inv;
  v.w = (v.w - mn) * inv;
  reinterpret_cast<float4*>(e)[t] = v;
}

extern "C" void kernel_launch(void* const* d_in, const int* in_sizes, int n_in,
                              void* d_out, int out_size, void* d_ws, size_t ws_size,
                              hipStream_t stream) {
  const float* x = (const float*)d_in[0];
  float* out = (float*)d_out;

  const size_t ws_needed = (size_t)(2 * NBLK) * sizeof(float);  // 2 KB
  if (ws_size >= ws_needed) {
    float* pm = (float*)d_ws;  // [NBLK min][NBLK max]
    entropy_kernel<0><<<dim3(NBLK), dim3(64, 16), 0, stream>>>(x, out, pm, nullptr);
    norm_ws<<<dim3(NPX4 / 256), dim3(256), 0, stream>>>(out, pm);
  } else {
    unsigned int* stats = (unsigned int*)d_ws;  // 8 uints
    hipMemsetAsync(stats, 0xFF, 4 * sizeof(unsigned int), stream);
    hipMemsetAsync(stats + 4, 0x00, 4 * sizeof(unsigned int), stream);
    entropy_kernel<1><<<dim3(NBLK), dim3(64, 16), 0, stream>>>(x, out, nullptr, stats);
    norm_atomic<<<dim3(NPX4 / 256), dim3(256), 0, stream>>>(out, stats);
  }
}